// Round 1
// baseline (102.570 us; speedup 1.0000x reference)
//
#include <hip/hip_runtime.h>

#define NB    4      // batches
#define NPTS  8192   // N == M
#define QPB   64     // query points per block (one per lane)
#define WPB   4      // waves per block

// Pack [B*N][3] fp32 points into float4 (x, y, z, 0.5*||p||^2) in workspace.
__global__ void pack_pts(const float* __restrict__ a, const float* __restrict__ b,
                         float4* __restrict__ pa, float4* __restrict__ pb, int n) {
    int i = blockIdx.x * blockDim.x + threadIdx.x;
    if (i < n) {
        float x = a[3 * i], y = a[3 * i + 1], z = a[3 * i + 2];
        pa[i] = make_float4(x, y, z, 0.5f * (x * x + y * y + z * z));
    } else if (i < 2 * n) {
        int j = i - n;
        float x = b[3 * j], y = b[3 * j + 1], z = b[3 * j + 2];
        pb[j] = make_float4(x, y, z, 0.5f * (x * x + y * y + z * z));
    }
}

// For each query point q: min over targets t of (t2h - q.t)  [== (||q-t||^2 - ||q||^2)/2]
// dist = max(2*(q2h + min_e), 0). Sum dists into accum[dir].
// Grid: x = NB * (NPTS/QPB) blocks, y = direction (0: q=p1,t=p2 ; 1: swapped).
// Block: 256 threads = 4 waves. Lane = query point; each wave scans NPTS/4 targets
// with a WAVE-UNIFORM index so target loads become s_load (scalar pipe, free vs VALU).
__launch_bounds__(256, 4)
__global__ void chamfer_min(const float4* __restrict__ p1, const float4* __restrict__ p2,
                            float* __restrict__ accum) {
    __shared__ float red[256];

    const int dir = blockIdx.y;
    const int bb  = blockIdx.x / (NPTS / QPB);
    const int blk = blockIdx.x % (NPTS / QPB);

    const float4* __restrict__ Q = (dir == 0 ? p1 : p2) + bb * NPTS;
    const float4* __restrict__ T = (dir == 0 ? p2 : p1) + bb * NPTS;

    const int lane = threadIdx.x & 63;
    // readfirstlane makes `wave` provably uniform -> target loads scalarize to s_load
    const int wave = __builtin_amdgcn_readfirstlane((int)(threadIdx.x >> 6));

    const float4 q = Q[blk * QPB + lane];

    const int mBeg = wave * (NPTS / WPB);
    float acc0 = 1e30f, acc1 = 1e30f;

#pragma unroll 8
    for (int m = 0; m < NPTS / WPB; m += 2) {
        float4 t0 = T[mBeg + m];
        float4 t1 = T[mBeg + m + 1];
        float d0 = q.x * t0.x + q.y * t0.y + q.z * t0.z;
        float d1 = q.x * t1.x + q.y * t1.y + q.z * t1.z;
        acc0 = fminf(acc0, t0.w - d0);
        acc1 = fminf(acc1, t1.w - d1);
    }
    float acc = fminf(acc0, acc1);

    red[threadIdx.x] = acc;
    __syncthreads();

    if (threadIdx.x < 64) {
        float v = fminf(fminf(red[lane], red[lane + 64]),
                        fminf(red[lane + 128], red[lane + 192]));
        float dist = fmaxf(2.0f * (q.w + v), 0.0f);
        // wave-wide sum (64 lanes)
        for (int off = 32; off > 0; off >>= 1)
            dist += __shfl_xor(dist, off, 64);
        if (lane == 0) atomicAdd(&accum[dir], dist);
    }
}

__global__ void finish(const float* __restrict__ accum, float* __restrict__ out) {
    out[0] = accum[0] * (1.0f / (NB * NPTS)) + accum[1] * (1.0f / (NB * NPTS));
}

extern "C" void kernel_launch(void* const* d_in, const int* in_sizes, int n_in,
                              void* d_out, int out_size, void* d_ws, size_t ws_size,
                              hipStream_t stream) {
    const float* in1 = (const float*)d_in[0];
    const float* in2 = (const float*)d_in[1];

    float*  wsf   = (float*)d_ws;
    float*  accum = wsf;                       // 2 floats
    float4* p1    = (float4*)(wsf + 16);       // 64B offset, 16B aligned
    float4* p2    = p1 + NB * NPTS;            // total ws use ~1 MB

    hipMemsetAsync(accum, 0, 2 * sizeof(float), stream);

    const int tot = NB * NPTS;  // 32768 points per input
    pack_pts<<<dim3((2 * tot + 255) / 256), 256, 0, stream>>>(in1, in2, p1, p2, tot);

    dim3 grid(NB * (NPTS / QPB), 2);   // 512 x 2 blocks
    chamfer_min<<<grid, 256, 0, stream>>>(p1, p2, accum);

    finish<<<1, 1, 0, stream>>>(accum, (float*)d_out);
}

// Round 2
// 72.879 us; speedup vs baseline: 1.4074x; 1.4074x over previous
//
#include <hip/hip_runtime.h>

#define NB    4      // batches
#define NPTS  8192   // N == M
#define QPB   64     // query points per block (one per lane)
#define WPB   8      // waves per block (512 threads)

typedef float v2f __attribute__((ext_vector_type(2)));

// Pair-of-targets SoA: (x0,x1),(y0,y1),(z0,z1),(w0,w1) with w = 0.5*||p||^2.
// Each v2f is a 64-bit aligned quantity -> lives in an aligned SGPR pair.
struct TPair { v2f xx, yy, zz, ww; };   // 32 B

// Repack inputs: float4 (x,y,z,0.5||p||^2) per point (query view) AND
// pair-SoA TPair per 2 points (target view), for both inputs.
__global__ void pack_pts(const float* __restrict__ a, const float* __restrict__ b,
                         float4* __restrict__ q4a, float4* __restrict__ q4b,
                         TPair* __restrict__ tpa, TPair* __restrict__ tpb) {
    const int npair = NB * NPTS / 2;
    int i = blockIdx.x * blockDim.x + threadIdx.x;   // [0, 2*npair)
    const float* src = a;
    float4* q4 = q4a;  TPair* tp = tpa;
    int p = i;
    if (i >= npair) { src = b; q4 = q4b; tp = tpb; p = i - npair; }

    float x0 = src[6*p+0], y0 = src[6*p+1], z0 = src[6*p+2];
    float x1 = src[6*p+3], y1 = src[6*p+4], z1 = src[6*p+5];
    float w0 = 0.5f * (x0*x0 + y0*y0 + z0*z0);
    float w1 = 0.5f * (x1*x1 + y1*y1 + z1*z1);
    q4[2*p]   = make_float4(x0, y0, z0, w0);
    q4[2*p+1] = make_float4(x1, y1, z1, w1);
    TPair t;
    t.xx = (v2f){x0, x1}; t.yy = (v2f){y0, y1};
    t.zz = (v2f){z0, z1}; t.ww = (v2f){w0, w1};
    tp[p] = t;
}

// One packed group: e[0:1] = w - q.t for two targets, then acc = min3(acc, e0, e1).
// All target operands arrive as SGPR pairs (wave-uniform loads); q components are
// pre-negated VGPR pairs. 5 VALU inst per 2 target pairs.
#define GROUP(XX, YY, ZZ, WW, ACC) do {                                        \
    v2f r_;                                                                    \
    asm("v_pk_mul_f32 %0, %1, %2"     : "=v"(r_) : "v"(nqx), "s"(XX));         \
    asm("v_pk_fma_f32 %0, %1, %2, %0" : "+v"(r_) : "v"(nqy), "s"(YY));         \
    asm("v_pk_fma_f32 %0, %1, %2, %0" : "+v"(r_) : "v"(nqz), "s"(ZZ));         \
    asm("v_pk_add_f32 %0, %0, %1"     : "+v"(r_) : "s"(WW));                   \
    asm("v_min3_f32 %0, %0, %1, %2"   : "+v"(ACC) : "v"(r_.x), "v"(r_.y));     \
} while (0)

// Grid: x = NB*(NPTS/QPB), y = dir. Block: 512 threads = 8 waves.
// Lane = query point (64 per block); each wave scans a wave-uniform slice of
// 512 target-pairs so all target loads scalarize to s_load (scalar pipe).
__launch_bounds__(512, 8)
__global__ void chamfer_min(const float4* __restrict__ q4a, const float4* __restrict__ q4b,
                            const TPair* __restrict__ tpa, const TPair* __restrict__ tpb,
                            float* __restrict__ accum) {
    __shared__ float red[512];

    const int dir = blockIdx.y;
    const int bb  = blockIdx.x / (NPTS / QPB);
    const int blk = blockIdx.x % (NPTS / QPB);

    const float4* __restrict__ Q = (dir == 0 ? q4a : q4b) + bb * NPTS;
    const TPair*  __restrict__ T = (dir == 0 ? tpb : tpa) + bb * (NPTS / 2);

    const int lane = threadIdx.x & 63;
    const int wave = __builtin_amdgcn_readfirstlane((int)(threadIdx.x >> 6));

    const float4 q = Q[blk * QPB + lane];
    v2f nqx = (v2f){-q.x, -q.x};
    v2f nqy = (v2f){-q.y, -q.y};
    v2f nqz = (v2f){-q.z, -q.z};

    const int PPW = NPTS / 2 / WPB;            // 512 pairs per wave
    const TPair* __restrict__ Tw = T + wave * PPW;

    float acc0 = 1e30f, acc1 = 1e30f, acc2 = 1e30f, acc3 = 1e30f;

    for (int p = 0; p < PPW; p += 4) {         // 8 targets per iteration
        TPair t0 = Tw[p + 0];
        TPair t1 = Tw[p + 1];
        TPair t2 = Tw[p + 2];
        TPair t3 = Tw[p + 3];
        GROUP(t0.xx, t0.yy, t0.zz, t0.ww, acc0);
        GROUP(t1.xx, t1.yy, t1.zz, t1.ww, acc1);
        GROUP(t2.xx, t2.yy, t2.zz, t2.ww, acc2);
        GROUP(t3.xx, t3.yy, t3.zz, t3.ww, acc3);
    }
    float acc = fminf(fminf(acc0, acc1), fminf(acc2, acc3));

    red[threadIdx.x] = acc;
    __syncthreads();

    if (threadIdx.x < 64) {
        float v = red[lane];
#pragma unroll
        for (int w = 1; w < WPB; ++w) v = fminf(v, red[lane + 64 * w]);
        float dist = fmaxf(2.0f * (q.w + v), 0.0f);
        for (int off = 32; off > 0; off >>= 1)
            dist += __shfl_xor(dist, off, 64);
        if (lane == 0) atomicAdd(&accum[dir], dist);
    }
}

__global__ void finish(const float* __restrict__ accum, float* __restrict__ out) {
    out[0] = (accum[0] + accum[1]) * (1.0f / (NB * NPTS));
}

extern "C" void kernel_launch(void* const* d_in, const int* in_sizes, int n_in,
                              void* d_out, int out_size, void* d_ws, size_t ws_size,
                              hipStream_t stream) {
    const float* in1 = (const float*)d_in[0];
    const float* in2 = (const float*)d_in[1];

    const int tot   = NB * NPTS;      // 32768 points per input
    const int npair = tot / 2;

    char* ws = (char*)d_ws;
    float*  accum = (float*)ws;                      // 2 floats
    float4* q4a   = (float4*)(ws + 256);
    float4* q4b   = q4a + tot;
    TPair*  tpa   = (TPair*)(q4b + tot);
    TPair*  tpb   = tpa + npair;                     // total ~2.1 MB

    hipMemsetAsync(accum, 0, 2 * sizeof(float), stream);

    pack_pts<<<dim3((2 * npair) / 256), 256, 0, stream>>>(in1, in2, q4a, q4b, tpa, tpb);

    dim3 grid(NB * (NPTS / QPB), 2);   // 512 x 2 blocks, 8 waves each = 8192 waves
    chamfer_min<<<grid, 512, 0, stream>>>(q4a, q4b, tpa, tpb, accum);

    finish<<<1, 1, 0, stream>>>(accum, (float*)d_out);
}

// Round 3
// 71.100 us; speedup vs baseline: 1.4426x; 1.0250x over previous
//
#include <hip/hip_runtime.h>

#define NB    4      // batches
#define NPTS  8192   // N == M
#define QPL   2      // queries per lane
#define QPB   (64 * QPL)   // 128 queries per block
#define WPB   8      // waves per block (512 threads)
#define UNR   8      // TPairs per inner iteration (8 pairs = 16 targets, 256 B)

typedef float v2f __attribute__((ext_vector_type(2)));

// Pair-of-targets SoA: (x0,x1),(y0,y1),(z0,z1),(w0,w1) with w = 0.5*||p||^2.
struct TPair { v2f xx, yy, zz, ww; };   // 32 B

__global__ void pack_pts(const float* __restrict__ a, const float* __restrict__ b,
                         float4* __restrict__ q4a, float4* __restrict__ q4b,
                         TPair* __restrict__ tpa, TPair* __restrict__ tpb) {
    const int npair = NB * NPTS / 2;
    int i = blockIdx.x * blockDim.x + threadIdx.x;   // [0, 2*npair)
    const float* src = a;
    float4* q4 = q4a;  TPair* tp = tpa;
    int p = i;
    if (i >= npair) { src = b; q4 = q4b; tp = tpb; p = i - npair; }

    float x0 = src[6*p+0], y0 = src[6*p+1], z0 = src[6*p+2];
    float x1 = src[6*p+3], y1 = src[6*p+4], z1 = src[6*p+5];
    float w0 = 0.5f * (x0*x0 + y0*y0 + z0*z0);
    float w1 = 0.5f * (x1*x1 + y1*y1 + z1*z1);
    q4[2*p]   = make_float4(x0, y0, z0, w0);
    q4[2*p+1] = make_float4(x1, y1, z1, w1);
    TPair t;
    t.xx = (v2f){x0, x1}; t.yy = (v2f){y0, y1};
    t.zz = (v2f){z0, z1}; t.ww = (v2f){w0, w1};
    tp[p] = t;
}

// e[0:1] = w - q.t for two targets (packed), then acc = min3(acc, e0, e1).
// Target operands are SGPR pairs (wave-uniform s_loads); 5 VALU / 2 targets.
#define GROUP(NQX, NQY, NQZ, XX, YY, ZZ, WW, ACC) do {                         \
    v2f r_;                                                                    \
    asm("v_pk_mul_f32 %0, %1, %2"     : "=v"(r_) : "v"(NQX), "s"(XX));         \
    asm("v_pk_fma_f32 %0, %1, %2, %0" : "+v"(r_) : "v"(NQY), "s"(YY));         \
    asm("v_pk_fma_f32 %0, %1, %2, %0" : "+v"(r_) : "v"(NQZ), "s"(ZZ));         \
    asm("v_pk_add_f32 %0, %0, %1"     : "+v"(r_) : "s"(WW));                   \
    asm("v_min3_f32 %0, %0, %1, %2"   : "+v"(ACC) : "v"(r_.x), "v"(r_.y));     \
} while (0)

// Grid: x = NB*(NPTS/QPB), y = dir. Block: 512 threads = 8 waves.
// Each lane owns TWO queries (lane, lane+64 of the block's 128-query slab);
// each wave scans a wave-uniform slice of targets via s_load (scalar pipe).
// 8-TPair batches amortize the all-or-nothing lgkmcnt(0) SMEM wait:
// 320 VALU issue-cycles per wait vs ~300cy L2 latency -> ~50% duty/wave x 4 waves/SIMD.
__launch_bounds__(512)
__global__ void chamfer_min(const float4* __restrict__ q4a, const float4* __restrict__ q4b,
                            const TPair* __restrict__ tpa, const TPair* __restrict__ tpb,
                            float* __restrict__ accum) {
    __shared__ float red[QPL][WPB][64];

    const int dir = blockIdx.y;
    const int bb  = blockIdx.x / (NPTS / QPB);
    const int blk = blockIdx.x % (NPTS / QPB);

    const float4* __restrict__ Q = (dir == 0 ? q4a : q4b) + bb * NPTS;
    const TPair*  __restrict__ T = (dir == 0 ? tpb : tpa) + bb * (NPTS / 2);

    const int lane = threadIdx.x & 63;
    const int wave = __builtin_amdgcn_readfirstlane((int)(threadIdx.x >> 6));

    const float4 qa = Q[blk * QPB + lane];
    const float4 qb = Q[blk * QPB + 64 + lane];
    v2f nax = (v2f){-qa.x, -qa.x}, nay = (v2f){-qa.y, -qa.y}, naz = (v2f){-qa.z, -qa.z};
    v2f nbx = (v2f){-qb.x, -qb.x}, nby = (v2f){-qb.y, -qb.y}, nbz = (v2f){-qb.z, -qb.z};

    const int PPW = NPTS / 2 / WPB;            // 512 TPairs per wave slice
    const TPair* __restrict__ Tw = T + wave * PPW;

    float aA0 = 1e30f, aA1 = 1e30f, aA2 = 1e30f, aA3 = 1e30f;
    float aB0 = 1e30f, aB1 = 1e30f, aB2 = 1e30f, aB3 = 1e30f;

#pragma unroll 1
    for (int p = 0; p < PPW; p += UNR) {
        // batch all loads (4x s_load_dwordx16), then one lgkmcnt(0), then 16 GROUPs
        TPair t0 = Tw[p + 0], t1 = Tw[p + 1], t2 = Tw[p + 2], t3 = Tw[p + 3];
        TPair t4 = Tw[p + 4], t5 = Tw[p + 5], t6 = Tw[p + 6], t7 = Tw[p + 7];
        GROUP(nax, nay, naz, t0.xx, t0.yy, t0.zz, t0.ww, aA0);
        GROUP(nbx, nby, nbz, t0.xx, t0.yy, t0.zz, t0.ww, aB0);
        GROUP(nax, nay, naz, t1.xx, t1.yy, t1.zz, t1.ww, aA1);
        GROUP(nbx, nby, nbz, t1.xx, t1.yy, t1.zz, t1.ww, aB1);
        GROUP(nax, nay, naz, t2.xx, t2.yy, t2.zz, t2.ww, aA2);
        GROUP(nbx, nby, nbz, t2.xx, t2.yy, t2.zz, t2.ww, aB2);
        GROUP(nax, nay, naz, t3.xx, t3.yy, t3.zz, t3.ww, aA3);
        GROUP(nbx, nby, nbz, t3.xx, t3.yy, t3.zz, t3.ww, aB3);
        GROUP(nax, nay, naz, t4.xx, t4.yy, t4.zz, t4.ww, aA0);
        GROUP(nbx, nby, nbz, t4.xx, t4.yy, t4.zz, t4.ww, aB0);
        GROUP(nax, nay, naz, t5.xx, t5.yy, t5.zz, t5.ww, aA1);
        GROUP(nbx, nby, nbz, t5.xx, t5.yy, t5.zz, t5.ww, aB1);
        GROUP(nax, nay, naz, t6.xx, t6.yy, t6.zz, t6.ww, aA2);
        GROUP(nbx, nby, nbz, t6.xx, t6.yy, t6.zz, t6.ww, aB2);
        GROUP(nax, nay, naz, t7.xx, t7.yy, t7.zz, t7.ww, aA3);
        GROUP(nbx, nby, nbz, t7.xx, t7.yy, t7.zz, t7.ww, aB3);
    }
    float accA = fminf(fminf(aA0, aA1), fminf(aA2, aA3));
    float accB = fminf(fminf(aB0, aB1), fminf(aB2, aB3));

    red[0][wave][lane] = accA;
    red[1][wave][lane] = accB;
    __syncthreads();

    if (threadIdx.x < 128) {
        const int q = threadIdx.x >> 6;   // wave0 -> query row 0 (its qa), wave1 -> row 1 (its qb)
        float v = red[q][0][lane];
#pragma unroll
        for (int w = 1; w < WPB; ++w) v = fminf(v, red[q][w][lane]);
        const float qw = (q == 0) ? qa.w : qb.w;
        float dist = fmaxf(2.0f * (qw + v), 0.0f);
        for (int off = 32; off > 0; off >>= 1)
            dist += __shfl_xor(dist, off, 64);
        if (lane == 0) atomicAdd(&accum[dir], dist);
    }
}

__global__ void finish(const float* __restrict__ accum, float* __restrict__ out) {
    out[0] = (accum[0] + accum[1]) * (1.0f / (NB * NPTS));
}

extern "C" void kernel_launch(void* const* d_in, const int* in_sizes, int n_in,
                              void* d_out, int out_size, void* d_ws, size_t ws_size,
                              hipStream_t stream) {
    const float* in1 = (const float*)d_in[0];
    const float* in2 = (const float*)d_in[1];

    const int tot   = NB * NPTS;      // 32768 points per input
    const int npair = tot / 2;

    char* ws = (char*)d_ws;
    float*  accum = (float*)ws;                      // 2 floats
    float4* q4a   = (float4*)(ws + 256);
    float4* q4b   = q4a + tot;
    TPair*  tpa   = (TPair*)(q4b + tot);             // 256B-aligned region
    TPair*  tpb   = tpa + npair;

    hipMemsetAsync(accum, 0, 2 * sizeof(float), stream);

    pack_pts<<<dim3((2 * npair) / 256), 256, 0, stream>>>(in1, in2, q4a, q4b, tpa, tpb);

    dim3 grid(NB * (NPTS / QPB), 2);   // 256 x 2 = 512 blocks, 8 waves each
    chamfer_min<<<grid, 512, 0, stream>>>(q4a, q4b, tpa, tpb, accum);

    finish<<<1, 1, 0, stream>>>(accum, (float*)d_out);
}